// Round 3
// baseline (208.994 us; speedup 1.0000x reference)
//
#include <hip/hip_runtime.h>
#include <cstdint>
#include <cstddef>

#define EPSC 1e-7f
#define EPS9 1e-9f
#define K4PI2 0.40528473456935108577f
#define NTOPK 10

__device__ __forceinline__ bool better(float v1, int i1, float v2, int i2) {
    return (v1 > v2) || ((v1 == v2) && (i1 < i2));
}

// mask accessor: wide (int32/float32 0-or-1) vs byte (uint8) layout
__device__ __forceinline__ bool mask_at(const unsigned char* mb, int i, int wide) {
    if (wide) return reinterpret_cast<const unsigned int*>(mb)[i] != 0u;
    return mb[i] != 0;
}

// valid-masked, clipped CIoU between gt (x1a..y2a, precomputed w1h1, atan1) and pred box pb
__device__ __forceinline__ float ciou_clip(float x1a, float y1a, float x2a, float y2a,
                                           float w1h1, float atan1,
                                           float4 pb, float at2) {
    float w2 = pb.z - pb.x, h2 = pb.w - pb.y + EPSC;
    float iw = fmaxf(fminf(x2a, pb.z) - fmaxf(x1a, pb.x), 0.f);
    float ih = fmaxf(fminf(y2a, pb.w) - fmaxf(y1a, pb.y), 0.f);
    float inter = iw * ih;
    float uni = w1h1 + w2 * h2 - inter;
    float iou = inter / (uni + EPSC);
    float cw = fmaxf(x2a, pb.z) - fminf(x1a, pb.x);
    float ch = fmaxf(y2a, pb.w) - fminf(y1a, pb.y);
    float c2 = cw * cw + ch * ch + EPSC;
    float dx = pb.x + pb.z - x1a - x2a;
    float dy = pb.y + pb.w - y1a - y2a;
    float rho2 = (dx * dx + dy * dy) * 0.25f;
    float dat = at2 - atan1;
    float vv = K4PI2 * dat * dat;
    float aa = vv / (vv - iou + (1.f + EPSC));
    return fmaxf(iou - (rho2 / c2 + vv * aa), 0.f);
}

// K0: detect mask_gt memory layout. wide iff all n/4 leading words are {0,1,1.0f}
__global__ void k_detect(const unsigned char* __restrict__ mask, int n, int* __restrict__ mode) {
    __shared__ int bad;
    if (threadIdx.x == 0) bad = 0;
    __syncthreads();
    const unsigned int* w = reinterpret_cast<const unsigned int*>(mask);
    int nw = n >> 2;
    for (int i = threadIdx.x; i < nw; i += 256) {
        unsigned int v = w[i];
        if (v != 0u && v != 1u && v != 0x3f800000u) atomicOr(&bad, 1);
    }
    __syncthreads();
    if (threadIdx.x == 0) mode[0] = bad ? 0 : 1;
}

// K1: atan(w2/h2) per (b,a)
__global__ void k_pred(const float* __restrict__ pd_bboxes, float* __restrict__ atanp, int BA) {
    int i = blockIdx.x * 256 + threadIdx.x;
    if (i >= BA) return;
    float4 pb = reinterpret_cast<const float4*>(pd_bboxes)[i];
    float w2 = pb.z - pb.x, h2 = pb.w - pb.y + EPSC;
    atanp[i] = atanf(w2 / h2);
}

// K2: per (b,m) block — align metric over anchors + exact top-10 (value desc, idx asc)
__global__ __launch_bounds__(256) void k_topk(
    const float* __restrict__ pd_scores, const float* __restrict__ pd_bboxes,
    const float* __restrict__ anc, const float* __restrict__ gt_labels,
    const float* __restrict__ gt_bboxes, const unsigned char* __restrict__ mask_gt,
    const float* __restrict__ atanp, const int* __restrict__ mode,
    int* __restrict__ count, int* __restrict__ win_idx, float* __restrict__ win_al,
    float* __restrict__ win_ov, int* __restrict__ win_fl,
    int A, int C, int M)
{
    int bid = blockIdx.x;            // b*M + m
    int b = bid / M;
    int tid = threadIdx.x;
    int wide = mode[0];

    if (!mask_at(mask_gt, bid, wide)) {  // gt invalid: zero claims for this row
        if (tid < NTOPK) {
            int o = bid * NTOPK + tid;
            win_fl[o] = 0; win_idx[o] = 0; win_al[o] = 0.f; win_ov[o] = 0.f;
        }
        return;
    }

    float4 g = reinterpret_cast<const float4*>(gt_bboxes)[bid];
    float x1a = g.x, y1a = g.y, x2a = g.z, y2a = g.w;
    float w1 = x2a - x1a, h1 = y2a - y1a + EPSC;
    float w1h1 = w1 * h1;
    float atan1 = atanf(w1 / h1);
    int lbl = (int)gt_labels[bid];

    const float4* pb4 = reinterpret_cast<const float4*>(pd_bboxes + (size_t)b * A * 4);
    const float*  ps  = pd_scores + (size_t)b * A * C;
    const float*  at  = atanp + (size_t)b * A;
    const float2* an2 = reinterpret_cast<const float2*>(anc);

    float tv[NTOPK], tov[NTOPK];
    int   ti[NTOPK], tfl[NTOPK];
#pragma unroll
    for (int j = 0; j < NTOPK; ++j) { tv[j] = -1.f; ti[j] = 0x7fffffff; tov[j] = 0.f; tfl[j] = 0; }

    for (int a = tid; a < A; a += 256) {
        float2 ap = an2[a];
        bool in = (ap.x - x1a > EPS9) & (ap.y - y1a > EPS9) &
                  (x2a - ap.x > EPS9) & (y2a - ap.y > EPS9);
        float val = 0.f, ovl = 0.f;
        if (in) {
            float4 pb = pb4[a];
            ovl = ciou_clip(x1a, y1a, x2a, y2a, w1h1, atan1, pb, at[a]);
            float sc = (lbl >= 0) ? ps[(size_t)a * C + lbl] : 0.f;
            float o2 = ovl * ovl;
            val = sqrtf(sc) * (o2 * o2 * o2);
        }
        // static-index insertion (keeps list in registers)
        if (better(val, a, tv[NTOPK - 1], ti[NTOPK - 1])) {
            tv[NTOPK - 1] = val; ti[NTOPK - 1] = a; tov[NTOPK - 1] = ovl; tfl[NTOPK - 1] = in ? 1 : 0;
#pragma unroll
            for (int j = NTOPK - 1; j > 0; --j) {
                if (better(tv[j], ti[j], tv[j - 1], ti[j - 1])) {
                    float fv = tv[j]; tv[j] = tv[j - 1]; tv[j - 1] = fv;
                    int   fi = ti[j]; ti[j] = ti[j - 1]; ti[j - 1] = fi;
                    float fo = tov[j]; tov[j] = tov[j - 1]; tov[j - 1] = fo;
                    int   ff = tfl[j]; tfl[j] = tfl[j - 1]; tfl[j - 1] = ff;
                }
            }
        }
    }

    // 10-round global tournament: (value desc, index asc) == lax.top_k tie-break
    __shared__ float swv[8];
    __shared__ int   swi[8];
    int lane = tid & 63, wid = tid >> 6;
    int base_o = bid * NTOPK;

    for (int k = 0; k < NTOPK; ++k) {
        float bv = -2.f; int bi = 0x7fffffff;
#pragma unroll
        for (int j = 0; j < NTOPK; ++j)
            if (better(tv[j], ti[j], bv, bi)) { bv = tv[j]; bi = ti[j]; }
#pragma unroll
        for (int off = 32; off > 0; off >>= 1) {
            float ov = __shfl_xor(bv, off);
            int   oi = __shfl_xor(bi, off);
            if (better(ov, oi, bv, bi)) { bv = ov; bi = oi; }
        }
        if (lane == 0) { swv[wid] = bv; swi[wid] = bi; }
        __syncthreads();
        if (tid == 0) {
            float gv = swv[0]; int gi = swi[0];
            for (int w = 1; w < 4; ++w)
                if (better(swv[w], swi[w], gv, gi)) { gv = swv[w]; gi = swi[w]; }
            swv[7] = gv; swi[7] = gi;
        }
        __syncthreads();
        int gbi = swi[7];
#pragma unroll
        for (int j = 0; j < NTOPK; ++j) {
            if (ti[j] == gbi) {      // unique owner (anchor indices unique across threads)
                int o = base_o + k;
                win_idx[o] = gbi; win_al[o] = tv[j]; win_ov[o] = tov[j]; win_fl[o] = tfl[j];
                if (tfl[j]) atomicAdd(&count[(size_t)b * A + gbi], 1);
                tv[j] = -2.f; ti[j] = 0x7fffffff;   // invalidate
            }
        }
    }
}

// K3: claim resolution. count==1 -> sole claimant; count>1 -> is_max over ALL m (first-max tie)
__global__ void k_resolve(
    const float* __restrict__ pd_scores, const float* __restrict__ pd_bboxes,
    const float* __restrict__ anc, const float* __restrict__ gt_labels,
    const float* __restrict__ gt_bboxes, const unsigned char* __restrict__ mask_gt,
    const float* __restrict__ atanp, const int* __restrict__ mode,
    const int* __restrict__ count, const int* __restrict__ win_idx,
    const float* __restrict__ win_al, const float* __restrict__ win_ov,
    const int* __restrict__ win_fl,
    int* __restrict__ claim_m, float* __restrict__ claim_al, float* __restrict__ claim_ov,
    int A, int C, int M, int total)
{
    int t = blockIdx.x * 256 + threadIdx.x;
    if (t >= total) return;
    int bm = t / NTOPK;
    int b = bm / M, m = bm % M;
    if (!win_fl[t]) return;
    int a = win_idx[t];
    size_t ba = (size_t)b * A + a;
    int cnt = count[ba];
    if (cnt == 1) {
        claim_m[ba] = m; claim_al[ba] = win_al[t]; claim_ov[ba] = win_ov[t];
        return;
    }
    // conflicted: argmax_m of valid-masked overlaps (benign identical-value race among claimants)
    int wide = mode[0];
    float4 pb = reinterpret_cast<const float4*>(pd_bboxes)[ba];
    float2 ap = reinterpret_cast<const float2*>(anc)[a];
    float at2 = atanp[ba];
    float best_ov = -1.f; int best_m = 0, best_valid = 0;
    for (int mm = 0; mm < M; ++mm) {
        float4 g = reinterpret_cast<const float4*>(gt_bboxes)[b * M + mm];
        bool in = (ap.x - g.x > EPS9) && (ap.y - g.y > EPS9) &&
                  (g.z - ap.x > EPS9) && (g.w - ap.y > EPS9);
        bool valid = in && mask_at(mask_gt, b * M + mm, wide);
        float ov = 0.f;
        if (valid) {
            float w1 = g.z - g.x, h1 = g.w - g.y + EPSC;
            ov = ciou_clip(g.x, g.y, g.z, g.w, w1 * h1, atanf(w1 / h1), pb, at2);
        }
        if (ov > best_ov) { best_ov = ov; best_m = mm; best_valid = valid ? 1 : 0; }
    }
    int lb = (int)gt_labels[b * M + best_m];
    float sc = (best_valid && lb >= 0) ? pd_scores[ba * C + lb] : 0.f;
    float o2 = best_ov * best_ov;
    claim_m[ba]  = best_m;
    claim_al[ba] = sqrtf(sc) * (o2 * o2 * o2);
    claim_ov[ba] = best_ov;
}

// K4: pos_align / pos_overlaps per gt via uint atomicMax (all values >= 0)
__global__ void k_posmax(const int* __restrict__ count, const int* __restrict__ claim_m,
                         const float* __restrict__ claim_al, const float* __restrict__ claim_ov,
                         float* __restrict__ pos_al, float* __restrict__ pos_ov,
                         int A, int M, int BA) {
    int ba = blockIdx.x * 256 + threadIdx.x;
    if (ba >= BA) return;
    if (count[ba] <= 0) return;
    int b = ba / A;
    int m = claim_m[ba];
    atomicMax((unsigned int*)&pos_al[b * M + m], __float_as_uint(claim_al[ba]));
    atomicMax((unsigned int*)&pos_ov[b * M + m], __float_as_uint(claim_ov[ba]));
}

// K5b: bboxes + fg + per-anchor (norm, label)
__global__ void k_fin1(const int* __restrict__ count, const int* __restrict__ claim_m,
                       const float* __restrict__ claim_al,
                       const float* __restrict__ pos_al, const float* __restrict__ pos_ov,
                       const float* __restrict__ gt_labels, const float* __restrict__ gt_bboxes,
                       float* __restrict__ out_bb, float* __restrict__ out_fg,
                       float* __restrict__ normv, int* __restrict__ lblv,
                       int A, int M, int BA) {
    int ba = blockIdx.x * 256 + threadIdx.x;
    if (ba >= BA) return;
    int b = ba / A;
    int cnt = count[ba];
    int m = claim_m[ba];                       // 0 for background (memset)
    float4 g = reinterpret_cast<const float4*>(gt_bboxes)[b * M + m];
    reinterpret_cast<float4*>(out_bb)[ba] = g;
    float nv = 0.f; int lb = -1;
    if (cnt > 0) {
        lb = max((int)gt_labels[b * M + m], 0);
        nv = claim_al[ba] * pos_ov[b * M + m] / (pos_al[b * M + m] + EPS9);
    }
    out_fg[ba] = (cnt > 0) ? 1.f : 0.f;
    normv[ba] = nv; lblv[ba] = lb;
}

// K5a: target_scores, float4-vectorized over classes
__global__ void k_scores(const float* __restrict__ normv, const int* __restrict__ lblv,
                         float* __restrict__ out_ts, int C4, int total4) {
    int i = blockIdx.x * 256 + threadIdx.x;
    if (i >= total4) return;
    int ba = i / C4;
    int c0 = (i - ba * C4) * 4;
    float nv = normv[ba];
    int lb = lblv[ba];
    float4 o;
    o.x = (c0     == lb) ? nv : 0.f;
    o.y = (c0 + 1 == lb) ? nv : 0.f;
    o.z = (c0 + 2 == lb) ? nv : 0.f;
    o.w = (c0 + 3 == lb) ? nv : 0.f;
    reinterpret_cast<float4*>(out_ts)[i] = o;
}

extern "C" void kernel_launch(void* const* d_in, const int* in_sizes, int n_in,
                              void* d_out, int out_size, void* d_ws, size_t ws_size,
                              hipStream_t stream) {
    const float* pd_scores = (const float*)d_in[0];
    const float* pd_bboxes = (const float*)d_in[1];
    const float* anc       = (const float*)d_in[2];
    const float* gt_labels = (const float*)d_in[3];
    const float* gt_bboxes = (const float*)d_in[4];
    const unsigned char* mask_gt = (const unsigned char*)d_in[5];

    int A  = in_sizes[2] / 2;
    int BA = in_sizes[1] / 4;
    int B  = BA / A;
    int C  = in_sizes[0] / BA;
    int M  = in_sizes[3] / B;
    int BM = B * M;

    // workspace carve (256B-aligned bumps; zeroed span is contiguous)
    char* w = (char*)d_ws;
    auto alloc = [&](size_t bytes) { char* p = w; w += ((bytes + 255) / 256) * 256; return p; };
    int*   mode     = (int*)  alloc(256);
    float* atanp    = (float*)alloc((size_t)BA * 4);
    char*  zero_beg = w;
    int*   count    = (int*)  alloc((size_t)BA * 4);
    int*   claim_m  = (int*)  alloc((size_t)BA * 4);
    float* claim_al = (float*)alloc((size_t)BA * 4);
    float* claim_ov = (float*)alloc((size_t)BA * 4);
    float* pos_al   = (float*)alloc((size_t)BM * 4);
    float* pos_ov   = (float*)alloc((size_t)BM * 4);
    char*  zero_end = w;
    int*   win_idx  = (int*)  alloc((size_t)BM * NTOPK * 4);
    float* win_al   = (float*)alloc((size_t)BM * NTOPK * 4);
    float* win_ov   = (float*)alloc((size_t)BM * NTOPK * 4);
    int*   win_fl   = (int*)  alloc((size_t)BM * NTOPK * 4);
    float* normv    = (float*)alloc((size_t)BA * 4);
    int*   lblv     = (int*)  alloc((size_t)BA * 4);

    float* out_bb = (float*)d_out;
    float* out_ts = out_bb + (size_t)BA * 4;
    float* out_fg = out_ts + (size_t)BA * C;

    hipMemsetAsync(zero_beg, 0, (size_t)(zero_end - zero_beg), stream);

    int gBA = (BA + 255) / 256;
    k_detect<<<1, 256, 0, stream>>>(mask_gt, BM, mode);
    k_pred<<<gBA, 256, 0, stream>>>(pd_bboxes, atanp, BA);
    k_topk<<<BM, 256, 0, stream>>>(pd_scores, pd_bboxes, anc, gt_labels, gt_bboxes, mask_gt,
                                   atanp, mode, count, win_idx, win_al, win_ov, win_fl, A, C, M);
    int nclaims = BM * NTOPK;
    k_resolve<<<(nclaims + 255) / 256, 256, 0, stream>>>(
        pd_scores, pd_bboxes, anc, gt_labels, gt_bboxes, mask_gt, atanp, mode,
        count, win_idx, win_al, win_ov, win_fl, claim_m, claim_al, claim_ov, A, C, M, nclaims);
    k_posmax<<<gBA, 256, 0, stream>>>(count, claim_m, claim_al, claim_ov, pos_al, pos_ov, A, M, BA);
    k_fin1<<<gBA, 256, 0, stream>>>(count, claim_m, claim_al, pos_al, pos_ov,
                                    gt_labels, gt_bboxes, out_bb, out_fg, normv, lblv, A, M, BA);
    int C4 = C / 4;
    int total4 = BA * C4;
    k_scores<<<(total4 + 255) / 256, 256, 0, stream>>>(normv, lblv, out_ts, C4, total4);
}

// Round 4
// 105.237 us; speedup vs baseline: 1.9859x; 1.9859x over previous
//
#include <hip/hip_runtime.h>
#include <cstdint>
#include <cstddef>

#define EPSC 1e-7f
#define EPS9 1e-9f
#define K4PI2 0.40528473456935108577f
#define NTOPK 10
#define NCAP 1536

__device__ __forceinline__ bool better(float v1, int i1, float v2, int i2) {
    return (v1 > v2) || ((v1 == v2) && (i1 < i2));
}

// mask accessor: wide (int32/float32 0-or-1) vs byte (uint8) layout
__device__ __forceinline__ bool mask_at(const unsigned char* mb, int i, int wide) {
    if (wide) return reinterpret_cast<const unsigned int*>(mb)[i] != 0u;
    return mb[i] != 0;
}

__device__ __forceinline__ unsigned long long shfl_xor_u64(unsigned long long v, int off) {
    int lo = __shfl_xor((int)(unsigned)(v & 0xFFFFFFFFull), off);
    int hi = __shfl_xor((int)(unsigned)(v >> 32), off);
    return ((unsigned long long)(unsigned)hi << 32) | (unsigned)lo;
}

// valid-masked, clipped CIoU between gt (precomputed w1h1, atan1) and pred box pb
__device__ __forceinline__ float ciou_clip(float x1a, float y1a, float x2a, float y2a,
                                           float w1h1, float atan1,
                                           float4 pb, float at2) {
    float w2 = pb.z - pb.x, h2 = pb.w - pb.y + EPSC;
    float iw = fmaxf(fminf(x2a, pb.z) - fmaxf(x1a, pb.x), 0.f);
    float ih = fmaxf(fminf(y2a, pb.w) - fmaxf(y1a, pb.y), 0.f);
    float inter = iw * ih;
    float uni = w1h1 + w2 * h2 - inter;
    float iou = inter / (uni + EPSC);
    float cw = fmaxf(x2a, pb.z) - fminf(x1a, pb.x);
    float ch = fmaxf(y2a, pb.w) - fminf(y1a, pb.y);
    float c2 = cw * cw + ch * ch + EPSC;
    float dx = pb.x + pb.z - x1a - x2a;
    float dy = pb.y + pb.w - y1a - y2a;
    float rho2 = (dx * dx + dy * dy) * 0.25f;
    float dat = at2 - atan1;
    float vv = K4PI2 * dat * dat;
    float aa = vv / (vv - iou + (1.f + EPSC));
    return fmaxf(iou - (rho2 / c2 + vv * aa), 0.f);
}

// K0: detect mask_gt memory layout. wide iff all n/4 leading words are {0,1,1.0f}
__global__ void k_detect(const unsigned char* __restrict__ mask, int n, int* __restrict__ mode) {
    __shared__ int bad;
    if (threadIdx.x == 0) bad = 0;
    __syncthreads();
    const unsigned int* w = reinterpret_cast<const unsigned int*>(mask);
    int nw = n >> 2;
    for (int i = threadIdx.x; i < nw; i += 256) {
        unsigned int v = w[i];
        if (v != 0u && v != 1u && v != 0x3f800000u) atomicOr(&bad, 1);
    }
    __syncthreads();
    if (threadIdx.x == 0) mode[0] = bad ? 0 : 1;
}

// K2: per (b,m) block — compact in-box anchors to LDS, compute metric densely,
// 10-round u64-key tournament == lax.top_k (value desc, idx asc).
__global__ __launch_bounds__(256) void k_topk(
    const float* __restrict__ pd_scores, const float* __restrict__ pd_bboxes,
    const float* __restrict__ anc, const float* __restrict__ gt_labels,
    const float* __restrict__ gt_bboxes, const unsigned char* __restrict__ mask_gt,
    const int* __restrict__ mode,
    int* __restrict__ count, int* __restrict__ win_idx, float* __restrict__ win_al,
    float* __restrict__ win_ov, int* __restrict__ win_fl, int* __restrict__ ovf,
    int A, int C, int M)
{
    __shared__ unsigned long long keys[NCAP];
    __shared__ float ovls[NCAP];
    __shared__ int s_n, s_p;
    __shared__ unsigned long long s_red[4];

    int bid = blockIdx.x;            // b*M + m
    int b = bid / M;
    int tid = threadIdx.x;
    if (!mask_at(mask_gt, bid, mode[0])) return;   // win_fl pre-zeroed -> no claims

    float4 g = reinterpret_cast<const float4*>(gt_bboxes)[bid];
    float x1a = g.x, y1a = g.y, x2a = g.z, y2a = g.w;
    float w1 = x2a - x1a, h1 = y2a - y1a + EPSC;
    float w1h1 = w1 * h1;
    float atan1 = atanf(w1 / h1);
    int lbl = (int)gt_labels[bid];

    const float4* pb4 = reinterpret_cast<const float4*>(pd_bboxes + (size_t)b * A * 4);
    const float*  ps  = pd_scores + (size_t)b * A * C;
    const float2* an2 = reinterpret_cast<const float2*>(anc);

    if (tid == 0) { s_n = 0; s_p = 0; }
    __syncthreads();

    // Phase 1: in-box test only; compact indices
    for (int a = tid; a < A; a += 256) {
        float2 ap = an2[a];
        bool in = (ap.x - x1a > EPS9) & (ap.y - y1a > EPS9) &
                  (x2a - ap.x > EPS9) & (y2a - ap.y > EPS9);
        if (in) {
            int pos = atomicAdd(&s_n, 1);
            if (pos < NCAP) keys[pos] = (unsigned long long)(unsigned)a;
        }
    }
    __syncthreads();
    int n = s_n;
    if (n > NCAP) {              // pathological giant gt: defer to fallback kernel
        if (tid == 0) ovf[bid] = 1;
        return;
    }

    // Phase 2: dense metric compute over compacted candidates
    for (int i = tid; i < n; i += 256) {
        int a = (int)(unsigned)keys[i];
        float4 pb = pb4[a];
        float w2 = pb.z - pb.x, h2 = pb.w - pb.y + EPSC;
        float at2 = atanf(w2 / h2);
        float ovl = ciou_clip(x1a, y1a, x2a, y2a, w1h1, atan1, pb, at2);
        float sc = (lbl >= 0) ? ps[(size_t)a * C + lbl] : 0.f;
        float o2 = ovl * ovl;
        float val = sqrtf(sc) * (o2 * o2 * o2);
        // key max-order == (val desc, idx asc); val>=0 so float bits are monotone
        keys[i] = ((unsigned long long)__float_as_uint(val) << 32) | (unsigned)(~(unsigned)a);
        ovls[i] = ovl;
        if (val > 0.f) atomicAdd(&s_p, 1);
    }
    __syncthreads();
    int p = s_p;
    int rp = p < NTOPK ? p : NTOPK;
    int lane = tid & 63, wid = tid >> 6;
    int base_o = bid * NTOPK;

    // Phase 3a: positive rounds
    for (int k = 0; k < rp; ++k) {
        unsigned long long best = 0;
        for (int i = tid; i < n; i += 256) { unsigned long long kk = keys[i]; if (kk > best) best = kk; }
#pragma unroll
        for (int off = 32; off; off >>= 1) {
            unsigned long long o = shfl_xor_u64(best, off);
            if (o > best) best = o;
        }
        if (lane == 0) s_red[wid] = best;
        __syncthreads();
        unsigned long long kmax = s_red[0];
        for (int w = 1; w < 4; ++w) if (s_red[w] > kmax) kmax = s_red[w];
        for (int i = tid; i < n; i += 256) {
            if (keys[i] == kmax) {   // unique owner (keys unique by idx)
                int a = (int)(~(unsigned)(kmax & 0xFFFFFFFFull));
                int o = base_o + k;
                win_idx[o] = a;
                win_al[o]  = __uint_as_float((unsigned)(kmax >> 32));
                win_ov[o]  = ovls[i];
                win_fl[o]  = 1;
                atomicAdd(&count[(size_t)b * A + a], 1);
                keys[i] = 0;
            }
        }
        __syncthreads();
    }

    // Phase 3b (rare: fewer than 10 positives): fill slots with smallest-index zero-val
    // anchors; in-box zero-val ones (compacted, val==0) become real zero-metric claims.
    if (rp < NTOPK) {
        int iters = (A - tid + 255) / 256;   // #anchors a = tid + j*256 < A
        int zp = 0;                          // resume pointer over out-of-box zeros
        for (int k = rp; k < NTOPK; ++k) {
            unsigned zprop = 0xFFFFFFFFu;    // next out-of-box anchor (val==0, never a claim)
            while (zp < iters) {
                int a = tid + zp * 256;
                float2 ap = an2[a];
                bool in = (ap.x - x1a > EPS9) & (ap.y - y1a > EPS9) &
                          (x2a - ap.x > EPS9) & (y2a - ap.y > EPS9);
                if (!in) { zprop = (unsigned)a; break; }
                ++zp;
            }
            unsigned cprop = 0xFFFFFFFFu; int cpos = -1;   // unconsumed compacted zero-val
            for (int i = tid; i < n; i += 256) {
                unsigned long long kk = keys[i];
                if (kk != 0ull && kk < (1ull << 32)) {
                    unsigned idx2 = ~(unsigned)kk;
                    if (idx2 < cprop) { cprop = idx2; cpos = i; }
                }
            }
            unsigned prop = zprop < cprop ? zprop : cprop;
            unsigned bm_ = prop;
#pragma unroll
            for (int off = 32; off; off >>= 1) {
                unsigned o = (unsigned)__shfl_xor((int)bm_, off);
                if (o < bm_) bm_ = o;
            }
            if (lane == 0) s_red[wid] = bm_;
            __syncthreads();
            unsigned pmin = (unsigned)s_red[0];
            for (int w = 1; w < 4; ++w) { unsigned v = (unsigned)s_red[w]; if (v < pmin) pmin = v; }
            if (pmin != 0xFFFFFFFFu) {
                if (cpos >= 0 && cprop == pmin && cprop < zprop) {
                    // in-box zero-metric claim (matches reference mask_pos semantics)
                    int o = base_o + k;
                    win_idx[o] = (int)pmin; win_al[o] = 0.f; win_ov[o] = ovls[cpos]; win_fl[o] = 1;
                    atomicAdd(&count[(size_t)b * A + pmin], 1);
                    keys[cpos] = 0;
                } else if (zprop == pmin && zprop < cprop) {
                    ++zp;   // consume out-of-box zero; padding slot, no claim
                }
            }
            __syncthreads();
        }
    }
}

// K2fb: exact fallback (round-3 algorithm) for blocks whose in-box count > NCAP
__global__ __launch_bounds__(256) void k_topk_fb(
    const float* __restrict__ pd_scores, const float* __restrict__ pd_bboxes,
    const float* __restrict__ anc, const float* __restrict__ gt_labels,
    const float* __restrict__ gt_bboxes,
    const int* __restrict__ ovf,
    int* __restrict__ count, int* __restrict__ win_idx, float* __restrict__ win_al,
    float* __restrict__ win_ov, int* __restrict__ win_fl,
    int A, int C, int M)
{
    int bid = blockIdx.x;
    if (!ovf[bid]) return;
    int b = bid / M;
    int tid = threadIdx.x;

    float4 g = reinterpret_cast<const float4*>(gt_bboxes)[bid];
    float x1a = g.x, y1a = g.y, x2a = g.z, y2a = g.w;
    float w1 = x2a - x1a, h1 = y2a - y1a + EPSC;
    float w1h1 = w1 * h1;
    float atan1 = atanf(w1 / h1);
    int lbl = (int)gt_labels[bid];

    const float4* pb4 = reinterpret_cast<const float4*>(pd_bboxes + (size_t)b * A * 4);
    const float*  ps  = pd_scores + (size_t)b * A * C;
    const float2* an2 = reinterpret_cast<const float2*>(anc);

    float tv[NTOPK], tov[NTOPK];
    int   ti[NTOPK], tfl[NTOPK];
#pragma unroll
    for (int j = 0; j < NTOPK; ++j) { tv[j] = -1.f; ti[j] = 0x7fffffff; tov[j] = 0.f; tfl[j] = 0; }

    for (int a = tid; a < A; a += 256) {
        float2 ap = an2[a];
        bool in = (ap.x - x1a > EPS9) & (ap.y - y1a > EPS9) &
                  (x2a - ap.x > EPS9) & (y2a - ap.y > EPS9);
        float val = 0.f, ovl = 0.f;
        if (in) {
            float4 pb = pb4[a];
            float w2 = pb.z - pb.x, h2 = pb.w - pb.y + EPSC;
            ovl = ciou_clip(x1a, y1a, x2a, y2a, w1h1, atan1, pb, atanf(w2 / h2));
            float sc = (lbl >= 0) ? ps[(size_t)a * C + lbl] : 0.f;
            float o2 = ovl * ovl;
            val = sqrtf(sc) * (o2 * o2 * o2);
        }
        if (better(val, a, tv[NTOPK - 1], ti[NTOPK - 1])) {
            tv[NTOPK - 1] = val; ti[NTOPK - 1] = a; tov[NTOPK - 1] = ovl; tfl[NTOPK - 1] = in ? 1 : 0;
#pragma unroll
            for (int j = NTOPK - 1; j > 0; --j) {
                if (better(tv[j], ti[j], tv[j - 1], ti[j - 1])) {
                    float fv = tv[j]; tv[j] = tv[j - 1]; tv[j - 1] = fv;
                    int   fi = ti[j]; ti[j] = ti[j - 1]; ti[j - 1] = fi;
                    float fo = tov[j]; tov[j] = tov[j - 1]; tov[j - 1] = fo;
                    int   ff = tfl[j]; tfl[j] = tfl[j - 1]; tfl[j - 1] = ff;
                }
            }
        }
    }

    __shared__ float swv[8];
    __shared__ int   swi[8];
    int lane = tid & 63, wid = tid >> 6;
    int base_o = bid * NTOPK;

    for (int k = 0; k < NTOPK; ++k) {
        float bv = -2.f; int bi = 0x7fffffff;
#pragma unroll
        for (int j = 0; j < NTOPK; ++j)
            if (better(tv[j], ti[j], bv, bi)) { bv = tv[j]; bi = ti[j]; }
#pragma unroll
        for (int off = 32; off > 0; off >>= 1) {
            float ov = __shfl_xor(bv, off);
            int   oi = __shfl_xor(bi, off);
            if (better(ov, oi, bv, bi)) { bv = ov; bi = oi; }
        }
        if (lane == 0) { swv[wid] = bv; swi[wid] = bi; }
        __syncthreads();
        if (tid == 0) {
            float gv = swv[0]; int gi = swi[0];
            for (int w = 1; w < 4; ++w)
                if (better(swv[w], swi[w], gv, gi)) { gv = swv[w]; gi = swi[w]; }
            swv[7] = gv; swi[7] = gi;
        }
        __syncthreads();
        int gbi = swi[7];
#pragma unroll
        for (int j = 0; j < NTOPK; ++j) {
            if (ti[j] == gbi) {
                int o = base_o + k;
                win_idx[o] = gbi; win_al[o] = tv[j]; win_ov[o] = tov[j]; win_fl[o] = tfl[j];
                if (tfl[j]) atomicAdd(&count[(size_t)b * A + gbi], 1);
                tv[j] = -2.f; ti[j] = 0x7fffffff;
            }
        }
        __syncthreads();
    }
}

// K3: claim resolution + fused pos_al/pos_ov atomicMax.
__global__ void k_resolve(
    const float* __restrict__ pd_scores, const float* __restrict__ pd_bboxes,
    const float* __restrict__ anc, const float* __restrict__ gt_labels,
    const float* __restrict__ gt_bboxes, const unsigned char* __restrict__ mask_gt,
    const int* __restrict__ mode,
    const int* __restrict__ count, const int* __restrict__ win_idx,
    const float* __restrict__ win_al, const float* __restrict__ win_ov,
    const int* __restrict__ win_fl,
    int* __restrict__ claim_m, float* __restrict__ claim_al,
    float* __restrict__ pos_al, float* __restrict__ pos_ov,
    int A, int C, int M, int total)
{
    int t = blockIdx.x * 256 + threadIdx.x;
    if (t >= total) return;
    int bm = t / NTOPK;
    int b = bm / M, m = bm % M;
    if (!win_fl[t]) return;
    int a = win_idx[t];
    size_t ba = (size_t)b * A + a;
    int cnt = count[ba];
    float al, ov; int mm_out;
    if (cnt == 1) {
        mm_out = m; al = win_al[t]; ov = win_ov[t];
    } else {
        // conflicted: argmax_m of valid-masked overlaps (first-max tie; identical-value
        // writes among claimants are benign)
        int wide = mode[0];
        float4 pb = reinterpret_cast<const float4*>(pd_bboxes)[ba];
        float2 ap = reinterpret_cast<const float2*>(anc)[a];
        float w2 = pb.z - pb.x, h2p = pb.w - pb.y + EPSC;
        float at2 = atanf(w2 / h2p);
        float best_ov = -1.f; int best_m = 0, best_valid = 0;
        for (int mm = 0; mm < M; ++mm) {
            float4 gg = reinterpret_cast<const float4*>(gt_bboxes)[b * M + mm];
            bool in = (ap.x - gg.x > EPS9) && (ap.y - gg.y > EPS9) &&
                      (gg.z - ap.x > EPS9) && (gg.w - ap.y > EPS9);
            bool valid = in && mask_at(mask_gt, b * M + mm, wide);
            float ovv = 0.f;
            if (valid) {
                float w1 = gg.z - gg.x, h1 = gg.w - gg.y + EPSC;
                ovv = ciou_clip(gg.x, gg.y, gg.z, gg.w, w1 * h1, atanf(w1 / h1), pb, at2);
            }
            if (ovv > best_ov) { best_ov = ovv; best_m = mm; best_valid = valid ? 1 : 0; }
        }
        int lb = (int)gt_labels[b * M + best_m];
        float sc = (best_valid && lb >= 0) ? pd_scores[ba * C + lb] : 0.f;
        float o2 = best_ov * best_ov;
        mm_out = best_m; al = sqrtf(sc) * (o2 * o2 * o2); ov = best_ov;
    }
    claim_m[ba]  = mm_out;
    claim_al[ba] = al;
    atomicMax((unsigned int*)&pos_al[b * M + mm_out], __float_as_uint(al));
    atomicMax((unsigned int*)&pos_ov[b * M + mm_out], __float_as_uint(ov));
}

// K5b: bboxes + fg + per-anchor (norm, label)
__global__ void k_fin1(const int* __restrict__ count, const int* __restrict__ claim_m,
                       const float* __restrict__ claim_al,
                       const float* __restrict__ pos_al, const float* __restrict__ pos_ov,
                       const float* __restrict__ gt_labels, const float* __restrict__ gt_bboxes,
                       float* __restrict__ out_bb, float* __restrict__ out_fg,
                       float* __restrict__ normv, int* __restrict__ lblv,
                       int A, int M, int BA) {
    int ba = blockIdx.x * 256 + threadIdx.x;
    if (ba >= BA) return;
    int b = ba / A;
    int cnt = count[ba];
    int m = claim_m[ba];                       // 0 for background (memset)
    float4 g = reinterpret_cast<const float4*>(gt_bboxes)[b * M + m];
    reinterpret_cast<float4*>(out_bb)[ba] = g;
    float nv = 0.f; int lb = -1;
    if (cnt > 0) {
        lb = max((int)gt_labels[b * M + m], 0);
        nv = claim_al[ba] * pos_ov[b * M + m] / (pos_al[b * M + m] + EPS9);
    }
    out_fg[ba] = (cnt > 0) ? 1.f : 0.f;
    normv[ba] = nv; lblv[ba] = lb;
}

// K5a: target_scores, float4-vectorized over classes
__global__ void k_scores(const float* __restrict__ normv, const int* __restrict__ lblv,
                         float* __restrict__ out_ts, int C4, int total4) {
    int i = blockIdx.x * 256 + threadIdx.x;
    if (i >= total4) return;
    int ba = i / C4;
    int c0 = (i - ba * C4) * 4;
    float nv = normv[ba];
    int lb = lblv[ba];
    float4 o;
    o.x = (c0     == lb) ? nv : 0.f;
    o.y = (c0 + 1 == lb) ? nv : 0.f;
    o.z = (c0 + 2 == lb) ? nv : 0.f;
    o.w = (c0 + 3 == lb) ? nv : 0.f;
    reinterpret_cast<float4*>(out_ts)[i] = o;
}

extern "C" void kernel_launch(void* const* d_in, const int* in_sizes, int n_in,
                              void* d_out, int out_size, void* d_ws, size_t ws_size,
                              hipStream_t stream) {
    const float* pd_scores = (const float*)d_in[0];
    const float* pd_bboxes = (const float*)d_in[1];
    const float* anc       = (const float*)d_in[2];
    const float* gt_labels = (const float*)d_in[3];
    const float* gt_bboxes = (const float*)d_in[4];
    const unsigned char* mask_gt = (const unsigned char*)d_in[5];

    int A  = in_sizes[2] / 2;
    int BA = in_sizes[1] / 4;
    int B  = BA / A;
    int C  = in_sizes[0] / BA;
    int M  = in_sizes[3] / B;
    int BM = B * M;

    // workspace carve (256B-aligned bumps; zeroed span is contiguous)
    char* w = (char*)d_ws;
    auto alloc = [&](size_t bytes) { char* p = w; w += ((bytes + 255) / 256) * 256; return p; };
    int*   mode     = (int*)  alloc(256);
    char*  zero_beg = w;
    int*   count    = (int*)  alloc((size_t)BA * 4);
    int*   claim_m  = (int*)  alloc((size_t)BA * 4);
    float* claim_al = (float*)alloc((size_t)BA * 4);
    float* pos_al   = (float*)alloc((size_t)BM * 4);
    float* pos_ov   = (float*)alloc((size_t)BM * 4);
    int*   win_fl   = (int*)  alloc((size_t)BM * NTOPK * 4);
    int*   ovf      = (int*)  alloc((size_t)BM * 4);
    char*  zero_end = w;
    int*   win_idx  = (int*)  alloc((size_t)BM * NTOPK * 4);
    float* win_al   = (float*)alloc((size_t)BM * NTOPK * 4);
    float* win_ov   = (float*)alloc((size_t)BM * NTOPK * 4);
    float* normv    = (float*)alloc((size_t)BA * 4);
    int*   lblv     = (int*)  alloc((size_t)BA * 4);

    float* out_bb = (float*)d_out;
    float* out_ts = out_bb + (size_t)BA * 4;
    float* out_fg = out_ts + (size_t)BA * C;

    hipMemsetAsync(zero_beg, 0, (size_t)(zero_end - zero_beg), stream);

    int gBA = (BA + 255) / 256;
    k_detect<<<1, 256, 0, stream>>>(mask_gt, BM, mode);
    k_topk<<<BM, 256, 0, stream>>>(pd_scores, pd_bboxes, anc, gt_labels, gt_bboxes, mask_gt,
                                   mode, count, win_idx, win_al, win_ov, win_fl, ovf, A, C, M);
    k_topk_fb<<<BM, 256, 0, stream>>>(pd_scores, pd_bboxes, anc, gt_labels, gt_bboxes,
                                      ovf, count, win_idx, win_al, win_ov, win_fl, A, C, M);
    int nclaims = BM * NTOPK;
    k_resolve<<<(nclaims + 255) / 256, 256, 0, stream>>>(
        pd_scores, pd_bboxes, anc, gt_labels, gt_bboxes, mask_gt, mode,
        count, win_idx, win_al, win_ov, win_fl, claim_m, claim_al, pos_al, pos_ov, A, C, M, nclaims);
    k_fin1<<<gBA, 256, 0, stream>>>(count, claim_m, claim_al, pos_al, pos_ov,
                                    gt_labels, gt_bboxes, out_bb, out_fg, normv, lblv, A, M, BA);
    int C4 = C / 4;
    int total4 = BA * C4;
    k_scores<<<(total4 + 255) / 256, 256, 0, stream>>>(normv, lblv, out_ts, C4, total4);
}

// Round 5
// 104.596 us; speedup vs baseline: 1.9981x; 1.0061x over previous
//
#include <hip/hip_runtime.h>
#include <cstdint>
#include <cstddef>

#define EPSC 1e-7f
#define EPS9 1e-9f
#define K4PI2 0.40528473456935108577f
#define NTOPK 10
#define NCAP 1536

__device__ __forceinline__ bool better(float v1, int i1, float v2, int i2) {
    return (v1 > v2) || ((v1 == v2) && (i1 < i2));
}

// mask accessor: wide (int32/float32 0-or-1) vs byte (uint8) layout
__device__ __forceinline__ bool mask_at(const unsigned char* mb, int i, int wide) {
    if (wide) return reinterpret_cast<const unsigned int*>(mb)[i] != 0u;
    return mb[i] != 0;
}

__device__ __forceinline__ unsigned long long shfl_xor_u64(unsigned long long v, int off) {
    int lo = __shfl_xor((int)(unsigned)(v & 0xFFFFFFFFull), off);
    int hi = __shfl_xor((int)(unsigned)(v >> 32), off);
    return ((unsigned long long)(unsigned)hi << 32) | (unsigned)lo;
}

__device__ __forceinline__ unsigned lane_rank(unsigned long long ball) {
    return __builtin_amdgcn_mbcnt_hi((unsigned)(ball >> 32),
           __builtin_amdgcn_mbcnt_lo((unsigned)(ball & 0xFFFFFFFFull), 0u));
}

// valid-masked, clipped CIoU between gt (precomputed w1h1, atan1) and pred box pb
__device__ __forceinline__ float ciou_clip(float x1a, float y1a, float x2a, float y2a,
                                           float w1h1, float atan1,
                                           float4 pb, float at2) {
    float w2 = pb.z - pb.x, h2 = pb.w - pb.y + EPSC;
    float iw = fmaxf(fminf(x2a, pb.z) - fmaxf(x1a, pb.x), 0.f);
    float ih = fmaxf(fminf(y2a, pb.w) - fmaxf(y1a, pb.y), 0.f);
    float inter = iw * ih;
    float uni = w1h1 + w2 * h2 - inter;
    float iou = inter / (uni + EPSC);
    float cw = fmaxf(x2a, pb.z) - fminf(x1a, pb.x);
    float ch = fmaxf(y2a, pb.w) - fminf(y1a, pb.y);
    float c2 = cw * cw + ch * ch + EPSC;
    float dx = pb.x + pb.z - x1a - x2a;
    float dy = pb.y + pb.w - y1a - y2a;
    float rho2 = (dx * dx + dy * dy) * 0.25f;
    float dat = at2 - atan1;
    float vv = K4PI2 * dat * dat;
    float aa = vv / (vv - iou + (1.f + EPSC));
    return fmaxf(iou - (rho2 / c2 + vv * aa), 0.f);
}

// K0: detect mask_gt memory layout. wide iff all n/4 leading words are {0,1,1.0f}
__global__ void k_detect(const unsigned char* __restrict__ mask, int n, int* __restrict__ mode) {
    __shared__ int bad;
    if (threadIdx.x == 0) bad = 0;
    __syncthreads();
    const unsigned int* w = reinterpret_cast<const unsigned int*>(mask);
    int nw = n >> 2;
    for (int i = threadIdx.x; i < nw; i += 256) {
        unsigned int v = w[i];
        if (v != 0u && v != 1u && v != 0x3f800000u) atomicOr(&bad, 1);
    }
    __syncthreads();
    if (threadIdx.x == 0) mode[0] = bad ? 0 : 1;
}

// K2: per (b,m) block — ballot-compact in-box anchors to LDS, dense metric compute,
// single-wave barrier-free 10-round u64 tournament == lax.top_k (value desc, idx asc).
__global__ __launch_bounds__(256) void k_topk(
    const float* __restrict__ pd_scores, const float* __restrict__ pd_bboxes,
    const float* __restrict__ anc, const float* __restrict__ gt_labels,
    const float* __restrict__ gt_bboxes, const unsigned char* __restrict__ mask_gt,
    const int* __restrict__ mode,
    int* __restrict__ count, int* __restrict__ win_idx, float* __restrict__ win_al,
    float* __restrict__ win_ov, int* __restrict__ win_fl, int* __restrict__ ovf,
    int A, int C, int M)
{
    __shared__ unsigned long long keys[NCAP];
    __shared__ float ovls[NCAP];
    __shared__ int s_n, s_p;

    int bid = blockIdx.x;            // b*M + m
    int b = bid / M;
    int tid = threadIdx.x;
    int lane = tid & 63;
    if (!mask_at(mask_gt, bid, mode[0])) return;   // win_fl pre-zeroed -> no claims

    float4 g = reinterpret_cast<const float4*>(gt_bboxes)[bid];
    float x1a = g.x, y1a = g.y, x2a = g.z, y2a = g.w;
    float w1 = x2a - x1a, h1 = y2a - y1a + EPSC;
    float w1h1 = w1 * h1;
    float atan1 = atanf(w1 / h1);
    int lbl = (int)gt_labels[bid];

    const float4* pb4 = reinterpret_cast<const float4*>(pd_bboxes + (size_t)b * A * 4);
    const float*  ps  = pd_scores + (size_t)b * A * C;
    const float2* an2 = reinterpret_cast<const float2*>(anc);

    if (tid == 0) { s_n = 0; s_p = 0; }
    __syncthreads();

    // Phase 1: in-box test; wave-aggregated compaction (one atomic per wave-iter)
    int it1 = (A + 255) / 256;
    for (int it = 0; it < it1; ++it) {
        int a = tid + it * 256;
        bool in = false;
        if (a < A) {
            float2 ap = an2[a];
            in = (ap.x - x1a > EPS9) & (ap.y - y1a > EPS9) &
                 (x2a - ap.x > EPS9) & (y2a - ap.y > EPS9);
        }
        unsigned long long ball = __ballot(in);
        if (ball) {
            int base2 = 0;
            if (lane == 0) base2 = atomicAdd(&s_n, __popcll(ball));
            base2 = __shfl(base2, 0);
            if (in) {
                int pos = base2 + (int)lane_rank(ball);
                if (pos < NCAP) keys[pos] = (unsigned long long)(unsigned)a;
            }
        }
    }
    __syncthreads();
    int n = s_n;
    if (n > NCAP) {              // pathological giant gt: defer to fallback kernel
        if (tid == 0) ovf[bid] = 1;
        return;
    }

    // Phase 2: dense metric compute over compacted candidates; ballot positive-count
    int it2 = (n + 255) / 256;
    int pc = 0;
    for (int it = 0; it < it2; ++it) {
        int i = tid + it * 256;
        bool act = i < n;
        float val = 0.f;
        if (act) {
            int a = (int)(unsigned)keys[i];
            float4 pb = pb4[a];
            float w2 = pb.z - pb.x, h2 = pb.w - pb.y + EPSC;
            float at2 = atanf(w2 / h2);
            float ovl = ciou_clip(x1a, y1a, x2a, y2a, w1h1, atan1, pb, at2);
            float sc = (lbl >= 0) ? ps[(size_t)a * C + lbl] : 0.f;
            float o2 = ovl * ovl;
            val = sqrtf(sc) * (o2 * o2 * o2);
            // key max-order == (val desc, idx asc); val>=0 so float bits are monotone
            keys[i] = ((unsigned long long)__float_as_uint(val) << 32) | (unsigned)(~(unsigned)a);
            ovls[i] = ovl;
        }
        pc += __popcll(__ballot(val > 0.f));
    }
    if (lane == 0 && pc) atomicAdd(&s_p, pc);
    __syncthreads();

    if (tid >= 64) return;       // Phase 3 is single-wave, barrier-free
    int p = s_p;
    int rp = p < NTOPK ? p : NTOPK;
    int base_o = bid * NTOPK;

    // Phase 3a: positive rounds (wave-synchronous; keys unique -> unique owner)
    for (int k = 0; k < rp; ++k) {
        unsigned long long lmax = 0; int lpos = -1;
        for (int i = lane; i < n; i += 64) {
            unsigned long long kk = keys[i];
            if (kk > lmax) { lmax = kk; lpos = i; }
        }
        unsigned long long best = lmax;
#pragma unroll
        for (int off = 32; off; off >>= 1) {
            unsigned long long o = shfl_xor_u64(best, off);
            if (o > best) best = o;
        }
        if (lpos >= 0 && lmax == best) {
            int a = (int)(~(unsigned)(best & 0xFFFFFFFFull));
            int o = base_o + k;
            win_idx[o] = a;
            win_al[o]  = __uint_as_float((unsigned)(best >> 32));
            win_ov[o]  = ovls[lpos];
            win_fl[o]  = 1;
            atomicAdd(&count[(size_t)b * A + a], 1);
            keys[lpos] = 0;      // re-read only by this lane next round
        }
    }

    // Phase 3b (rare: fewer than 10 positives): fill slots with smallest-index zero-val
    // anchors; in-box zero-val ones (compacted, val==0) become real zero-metric claims.
    if (rp < NTOPK) {
        int iters = (A + 63 - lane) / 64;    // #anchors a = lane + j*64 < A
        int zp = 0;                          // resume pointer over out-of-box zeros
        for (int k = rp; k < NTOPK; ++k) {
            unsigned zprop = 0xFFFFFFFFu;    // next out-of-box anchor (val==0, never a claim)
            while (zp < iters) {
                int a = lane + zp * 64;
                float2 ap = an2[a];
                bool in = (ap.x - x1a > EPS9) & (ap.y - y1a > EPS9) &
                          (x2a - ap.x > EPS9) & (y2a - ap.y > EPS9);
                if (!in) { zprop = (unsigned)a; break; }
                ++zp;
            }
            unsigned cprop = 0xFFFFFFFFu; int cpos = -1;   // unconsumed compacted zero-val
            for (int i = lane; i < n; i += 64) {
                unsigned long long kk = keys[i];
                if (kk != 0ull && kk < (1ull << 32)) {
                    unsigned idx2 = ~(unsigned)kk;
                    if (idx2 < cprop) { cprop = idx2; cpos = i; }
                }
            }
            unsigned prop = zprop < cprop ? zprop : cprop;
            unsigned bm_ = prop;
#pragma unroll
            for (int off = 32; off; off >>= 1) {
                unsigned o = (unsigned)__shfl_xor((int)bm_, off);
                if (o < bm_) bm_ = o;
            }
            if (bm_ != 0xFFFFFFFFu) {
                if (cpos >= 0 && cprop == bm_ && cprop < zprop) {
                    // in-box zero-metric claim (matches reference mask_pos semantics)
                    int o = base_o + k;
                    win_idx[o] = (int)bm_; win_al[o] = 0.f; win_ov[o] = ovls[cpos]; win_fl[o] = 1;
                    atomicAdd(&count[(size_t)b * A + bm_], 1);
                    keys[cpos] = 0;
                } else if (zprop == bm_ && zprop < cprop) {
                    ++zp;   // consume out-of-box zero; padding slot, no claim
                }
            }
        }
    }
}

// K2fb: exact fallback (round-3 algorithm) for blocks whose in-box count > NCAP
__global__ __launch_bounds__(256) void k_topk_fb(
    const float* __restrict__ pd_scores, const float* __restrict__ pd_bboxes,
    const float* __restrict__ anc, const float* __restrict__ gt_labels,
    const float* __restrict__ gt_bboxes,
    const int* __restrict__ ovf,
    int* __restrict__ count, int* __restrict__ win_idx, float* __restrict__ win_al,
    float* __restrict__ win_ov, int* __restrict__ win_fl,
    int A, int C, int M)
{
    int bid = blockIdx.x;
    if (!ovf[bid]) return;
    int b = bid / M;
    int tid = threadIdx.x;

    float4 g = reinterpret_cast<const float4*>(gt_bboxes)[bid];
    float x1a = g.x, y1a = g.y, x2a = g.z, y2a = g.w;
    float w1 = x2a - x1a, h1 = y2a - y1a + EPSC;
    float w1h1 = w1 * h1;
    float atan1 = atanf(w1 / h1);
    int lbl = (int)gt_labels[bid];

    const float4* pb4 = reinterpret_cast<const float4*>(pd_bboxes + (size_t)b * A * 4);
    const float*  ps  = pd_scores + (size_t)b * A * C;
    const float2* an2 = reinterpret_cast<const float2*>(anc);

    float tv[NTOPK], tov[NTOPK];
    int   ti[NTOPK], tfl[NTOPK];
#pragma unroll
    for (int j = 0; j < NTOPK; ++j) { tv[j] = -1.f; ti[j] = 0x7fffffff; tov[j] = 0.f; tfl[j] = 0; }

    for (int a = tid; a < A; a += 256) {
        float2 ap = an2[a];
        bool in = (ap.x - x1a > EPS9) & (ap.y - y1a > EPS9) &
                  (x2a - ap.x > EPS9) & (y2a - ap.y > EPS9);
        float val = 0.f, ovl = 0.f;
        if (in) {
            float4 pb = pb4[a];
            float w2 = pb.z - pb.x, h2 = pb.w - pb.y + EPSC;
            ovl = ciou_clip(x1a, y1a, x2a, y2a, w1h1, atan1, pb, atanf(w2 / h2));
            float sc = (lbl >= 0) ? ps[(size_t)a * C + lbl] : 0.f;
            float o2 = ovl * ovl;
            val = sqrtf(sc) * (o2 * o2 * o2);
        }
        if (better(val, a, tv[NTOPK - 1], ti[NTOPK - 1])) {
            tv[NTOPK - 1] = val; ti[NTOPK - 1] = a; tov[NTOPK - 1] = ovl; tfl[NTOPK - 1] = in ? 1 : 0;
#pragma unroll
            for (int j = NTOPK - 1; j > 0; --j) {
                if (better(tv[j], ti[j], tv[j - 1], ti[j - 1])) {
                    float fv = tv[j]; tv[j] = tv[j - 1]; tv[j - 1] = fv;
                    int   fi = ti[j]; ti[j] = ti[j - 1]; ti[j - 1] = fi;
                    float fo = tov[j]; tov[j] = tov[j - 1]; tov[j - 1] = fo;
                    int   ff = tfl[j]; tfl[j] = tfl[j - 1]; tfl[j - 1] = ff;
                }
            }
        }
    }

    __shared__ float swv[8];
    __shared__ int   swi[8];
    int lane = tid & 63, wid = tid >> 6;
    int base_o = bid * NTOPK;

    for (int k = 0; k < NTOPK; ++k) {
        float bv = -2.f; int bi = 0x7fffffff;
#pragma unroll
        for (int j = 0; j < NTOPK; ++j)
            if (better(tv[j], ti[j], bv, bi)) { bv = tv[j]; bi = ti[j]; }
#pragma unroll
        for (int off = 32; off > 0; off >>= 1) {
            float ov = __shfl_xor(bv, off);
            int   oi = __shfl_xor(bi, off);
            if (better(ov, oi, bv, bi)) { bv = ov; bi = oi; }
        }
        if (lane == 0) { swv[wid] = bv; swi[wid] = bi; }
        __syncthreads();
        if (tid == 0) {
            float gv = swv[0]; int gi = swi[0];
            for (int w = 1; w < 4; ++w)
                if (better(swv[w], swi[w], gv, gi)) { gv = swv[w]; gi = swi[w]; }
            swv[7] = gv; swi[7] = gi;
        }
        __syncthreads();
        int gbi = swi[7];
#pragma unroll
        for (int j = 0; j < NTOPK; ++j) {
            if (ti[j] == gbi) {
                int o = base_o + k;
                win_idx[o] = gbi; win_al[o] = tv[j]; win_ov[o] = tov[j]; win_fl[o] = tfl[j];
                if (tfl[j]) atomicAdd(&count[(size_t)b * A + gbi], 1);
                tv[j] = -2.f; ti[j] = 0x7fffffff;
            }
        }
        __syncthreads();
    }
}

// K3: claim resolution + fused pos_al/pos_ov atomicMax.
__global__ void k_resolve(
    const float* __restrict__ pd_scores, const float* __restrict__ pd_bboxes,
    const float* __restrict__ anc, const float* __restrict__ gt_labels,
    const float* __restrict__ gt_bboxes, const unsigned char* __restrict__ mask_gt,
    const int* __restrict__ mode,
    const int* __restrict__ count, const int* __restrict__ win_idx,
    const float* __restrict__ win_al, const float* __restrict__ win_ov,
    const int* __restrict__ win_fl,
    int* __restrict__ claim_m, float* __restrict__ claim_al,
    float* __restrict__ pos_al, float* __restrict__ pos_ov,
    int A, int C, int M, int total)
{
    int t = blockIdx.x * 256 + threadIdx.x;
    if (t >= total) return;
    int bm = t / NTOPK;
    int b = bm / M, m = bm % M;
    if (!win_fl[t]) return;
    int a = win_idx[t];
    size_t ba = (size_t)b * A + a;
    int cnt = count[ba];
    float al, ov; int mm_out;
    if (cnt == 1) {
        mm_out = m; al = win_al[t]; ov = win_ov[t];
    } else {
        // conflicted: argmax_m of valid-masked overlaps (first-max tie; identical-value
        // writes among claimants are benign)
        int wide = mode[0];
        float4 pb = reinterpret_cast<const float4*>(pd_bboxes)[ba];
        float2 ap = reinterpret_cast<const float2*>(anc)[a];
        float w2 = pb.z - pb.x, h2p = pb.w - pb.y + EPSC;
        float at2 = atanf(w2 / h2p);
        float best_ov = -1.f; int best_m = 0, best_valid = 0;
        for (int mm = 0; mm < M; ++mm) {
            float4 gg = reinterpret_cast<const float4*>(gt_bboxes)[b * M + mm];
            bool in = (ap.x - gg.x > EPS9) && (ap.y - gg.y > EPS9) &&
                      (gg.z - ap.x > EPS9) && (gg.w - ap.y > EPS9);
            bool valid = in && mask_at(mask_gt, b * M + mm, wide);
            float ovv = 0.f;
            if (valid) {
                float w1 = gg.z - gg.x, h1 = gg.w - gg.y + EPSC;
                ovv = ciou_clip(gg.x, gg.y, gg.z, gg.w, w1 * h1, atanf(w1 / h1), pb, at2);
            }
            if (ovv > best_ov) { best_ov = ovv; best_m = mm; best_valid = valid ? 1 : 0; }
        }
        int lb = (int)gt_labels[b * M + best_m];
        float sc = (best_valid && lb >= 0) ? pd_scores[ba * C + lb] : 0.f;
        float o2 = best_ov * best_ov;
        mm_out = best_m; al = sqrtf(sc) * (o2 * o2 * o2); ov = best_ov;
    }
    claim_m[ba]  = mm_out;
    claim_al[ba] = al;
    atomicMax((unsigned int*)&pos_al[b * M + mm_out], __float_as_uint(al));
    atomicMax((unsigned int*)&pos_ov[b * M + mm_out], __float_as_uint(ov));
}

// K5b: bboxes + fg + per-anchor (norm, label)
__global__ void k_fin1(const int* __restrict__ count, const int* __restrict__ claim_m,
                       const float* __restrict__ claim_al,
                       const float* __restrict__ pos_al, const float* __restrict__ pos_ov,
                       const float* __restrict__ gt_labels, const float* __restrict__ gt_bboxes,
                       float* __restrict__ out_bb, float* __restrict__ out_fg,
                       float* __restrict__ normv, int* __restrict__ lblv,
                       int A, int M, int BA) {
    int ba = blockIdx.x * 256 + threadIdx.x;
    if (ba >= BA) return;
    int b = ba / A;
    int cnt = count[ba];
    int m = claim_m[ba];                       // 0 for background (memset)
    float4 g = reinterpret_cast<const float4*>(gt_bboxes)[b * M + m];
    reinterpret_cast<float4*>(out_bb)[ba] = g;
    float nv = 0.f; int lb = -1;
    if (cnt > 0) {
        lb = max((int)gt_labels[b * M + m], 0);
        nv = claim_al[ba] * pos_ov[b * M + m] / (pos_al[b * M + m] + EPS9);
    }
    out_fg[ba] = (cnt > 0) ? 1.f : 0.f;
    normv[ba] = nv; lblv[ba] = lb;
}

// K5a: target_scores, float4-vectorized over classes
__global__ void k_scores(const float* __restrict__ normv, const int* __restrict__ lblv,
                         float* __restrict__ out_ts, int C4, int total4) {
    int i = blockIdx.x * 256 + threadIdx.x;
    if (i >= total4) return;
    int ba = i / C4;
    int c0 = (i - ba * C4) * 4;
    float nv = normv[ba];
    int lb = lblv[ba];
    float4 o;
    o.x = (c0     == lb) ? nv : 0.f;
    o.y = (c0 + 1 == lb) ? nv : 0.f;
    o.z = (c0 + 2 == lb) ? nv : 0.f;
    o.w = (c0 + 3 == lb) ? nv : 0.f;
    reinterpret_cast<float4*>(out_ts)[i] = o;
}

extern "C" void kernel_launch(void* const* d_in, const int* in_sizes, int n_in,
                              void* d_out, int out_size, void* d_ws, size_t ws_size,
                              hipStream_t stream) {
    const float* pd_scores = (const float*)d_in[0];
    const float* pd_bboxes = (const float*)d_in[1];
    const float* anc       = (const float*)d_in[2];
    const float* gt_labels = (const float*)d_in[3];
    const float* gt_bboxes = (const float*)d_in[4];
    const unsigned char* mask_gt = (const unsigned char*)d_in[5];

    int A  = in_sizes[2] / 2;
    int BA = in_sizes[1] / 4;
    int B  = BA / A;
    int C  = in_sizes[0] / BA;
    int M  = in_sizes[3] / B;
    int BM = B * M;

    // workspace carve (256B-aligned bumps; zeroed span is contiguous)
    char* w = (char*)d_ws;
    auto alloc = [&](size_t bytes) { char* p = w; w += ((bytes + 255) / 256) * 256; return p; };
    int*   mode     = (int*)  alloc(256);
    char*  zero_beg = w;
    int*   count    = (int*)  alloc((size_t)BA * 4);
    int*   claim_m  = (int*)  alloc((size_t)BA * 4);
    float* claim_al = (float*)alloc((size_t)BA * 4);
    float* pos_al   = (float*)alloc((size_t)BM * 4);
    float* pos_ov   = (float*)alloc((size_t)BM * 4);
    int*   win_fl   = (int*)  alloc((size_t)BM * NTOPK * 4);
    int*   ovf      = (int*)  alloc((size_t)BM * 4);
    char*  zero_end = w;
    int*   win_idx  = (int*)  alloc((size_t)BM * NTOPK * 4);
    float* win_al   = (float*)alloc((size_t)BM * NTOPK * 4);
    float* win_ov   = (float*)alloc((size_t)BM * NTOPK * 4);
    float* normv    = (float*)alloc((size_t)BA * 4);
    int*   lblv     = (int*)  alloc((size_t)BA * 4);

    float* out_bb = (float*)d_out;
    float* out_ts = out_bb + (size_t)BA * 4;
    float* out_fg = out_ts + (size_t)BA * C;

    hipMemsetAsync(zero_beg, 0, (size_t)(zero_end - zero_beg), stream);

    int gBA = (BA + 255) / 256;
    k_detect<<<1, 256, 0, stream>>>(mask_gt, BM, mode);
    k_topk<<<BM, 256, 0, stream>>>(pd_scores, pd_bboxes, anc, gt_labels, gt_bboxes, mask_gt,
                                   mode, count, win_idx, win_al, win_ov, win_fl, ovf, A, C, M);
    k_topk_fb<<<BM, 256, 0, stream>>>(pd_scores, pd_bboxes, anc, gt_labels, gt_bboxes,
                                      ovf, count, win_idx, win_al, win_ov, win_fl, A, C, M);
    int nclaims = BM * NTOPK;
    k_resolve<<<(nclaims + 255) / 256, 256, 0, stream>>>(
        pd_scores, pd_bboxes, anc, gt_labels, gt_bboxes, mask_gt, mode,
        count, win_idx, win_al, win_ov, win_fl, claim_m, claim_al, pos_al, pos_ov, A, C, M, nclaims);
    k_fin1<<<gBA, 256, 0, stream>>>(count, claim_m, claim_al, pos_al, pos_ov,
                                    gt_labels, gt_bboxes, out_bb, out_fg, normv, lblv, A, M, BA);
    int C4 = C / 4;
    int total4 = BA * C4;
    k_scores<<<(total4 + 255) / 256, 256, 0, stream>>>(normv, lblv, out_ts, C4, total4);
}